// Round 1
// baseline (1162.441 us; speedup 1.0000x reference)
//
#include <hip/hip_runtime.h>
#include <hip/hip_bf16.h>

#define NGRP 15552                 // B*L = 64*243
#define RROWS 264384               // NGRP*17
#define EPSV 1e-5f

typedef __attribute__((ext_vector_type(8))) short s16x8;
typedef __attribute__((ext_vector_type(4))) float f32x4;
typedef __hip_bfloat16 bf16;

__device__ __forceinline__ float bf2f(unsigned short u) {
    union { unsigned int i; float f; } x; x.i = ((unsigned int)u) << 16; return x.f;
}
__device__ __forceinline__ unsigned short f2bf(float f) {
    bf16 b = __float2bfloat16(f);
    return *reinterpret_cast<unsigned short*>(&b);
}

// ---------------- K0: weight prep ----------------
__global__ __launch_bounds__(256)
void k_prep(const float* __restrict__ w1, const float* __restrict__ b1,
            const float* __restrict__ w2, const float* __restrict__ b2,
            const float* __restrict__ mw1, const float* __restrict__ mw2,
            const float* __restrict__ adj,
            bf16* __restrict__ wsum, bf16* __restrict__ w1m, bf16* __restrict__ w2m,
            float* __restrict__ bsum, float* __restrict__ srow, float* __restrict__ stats)
{
    const int idx = blockIdx.x * 256 + threadIdx.x;      // grid = 512 blocks -> 131072
    if (idx < 65536) wsum[idx] = __float2bfloat16(w1[idx] + w2[idx]);
    w1m[idx] = __float2bfloat16(mw1[idx]);               // 131072 elements exactly
    w2m[idx] = __float2bfloat16(mw2[idx]);
    if (idx < 256) bsum[idx] = b1[idx] + b2[idx];
    if (idx < 512) stats[idx] = 0.0f;
    if (idx < 17) {
        float s = 0.0f;
        for (int j = 0; j < 17; ++j) s += adj[idx * 17 + j];
        srow[idx] = s;
    }
}

// ---------------- K1: xa[n,i,:] = sum_j adj[i,j] x[n,j,:]  (fp32 -> bf16) ------
__global__ __launch_bounds__(256)
void k_agg(const float* __restrict__ x, const float* __restrict__ adj,
           bf16* __restrict__ xa)
{
    __shared__ float sadj[289];
    const int t = threadIdx.x;
    sadj[t < 289 ? t : 0] = adj[t < 289 ? t : 0];
    if (t < 33) sadj[256 + t] = adj[256 + t];
    __syncthreads();
    const size_t base = (size_t)blockIdx.x * (17 * 256) + t;
    float xv[17];
#pragma unroll
    for (int j = 0; j < 17; ++j) xv[j] = x[base + j * 256];
#pragma unroll
    for (int i = 0; i < 17; ++i) {
        float s = 0.0f;
#pragma unroll
        for (int j = 0; j < 17; ++j) s = fmaf(sadj[i * 17 + j], xv[j], s);
        xa[base + i * 256] = __float2bfloat16(s);
    }
}

// ---------------- GEMM-BT: C[m,n] = sum_k A[m,k]*Bw[n,k]  (bf16 MFMA) ----------
// EPI 0: relu(acc + srow[m%17]*bias[n]) -> bf16      (stage-1 GCN)
// EPI 1: relu(acc + bias[n])            -> bf16      (MLP fc1)
// EPI 2: acc + bias[n]                  -> fp32      (MLP fc2)
template<int KDIM, int EPI>
__global__ __launch_bounds__(256, 2)
void gemm_bt(const bf16* __restrict__ A, const bf16* __restrict__ Bw,
             void* __restrict__ Cout, int M,
             const float* __restrict__ bias, const float* __restrict__ srow)
{
    constexpr int LDK = 72;                    // padded LDS row stride (bf16 elems)
    __shared__ bf16 sA[128 * LDK];
    __shared__ bf16 sB[128 * LDK];
    const int tid  = threadIdx.x;
    const int wave = tid >> 6, lane = tid & 63;
    const int wm = (wave >> 1) * 64, wn = (wave & 1) * 64;
    const int quad = lane >> 4, l16 = lane & 15;
    const int m0 = blockIdx.y * 128;
    const int n0 = blockIdx.x * 128;
    const int ldc = gridDim.x * 128;

    f32x4 acc[4][4] = {};

    const int str = tid >> 3;                  // staging row (0..31, +32 per iter)
    const int stc = (tid & 7) * 8;             // staging col (bf16 elems)

    for (int kt = 0; kt < KDIM / 64; ++kt) {
        const int k0 = kt * 64;
#pragma unroll
        for (int i = 0; i < 4; ++i) {
            const int r = str + i * 32;
            int gr = m0 + r; gr = gr < M ? gr : M - 1;
            *(uint4*)(sA + r * LDK + stc) =
                *(const uint4*)(A + (size_t)gr * KDIM + k0 + stc);
        }
#pragma unroll
        for (int i = 0; i < 4; ++i) {
            const int r = str + i * 32;
            *(uint4*)(sB + r * LDK + stc) =
                *(const uint4*)(Bw + (size_t)(n0 + r) * KDIM + k0 + stc);
        }
        __syncthreads();
#pragma unroll
        for (int ks = 0; ks < 2; ++ks) {
            const int kk = ks * 32 + quad * 8;
            s16x8 af[4], bfr[4];
#pragma unroll
            for (int xx = 0; xx < 4; ++xx)
                af[xx] = *(const s16x8*)(sA + (wm + xx * 16 + l16) * LDK + kk);
#pragma unroll
            for (int xx = 0; xx < 4; ++xx)
                bfr[xx] = *(const s16x8*)(sB + (wn + xx * 16 + l16) * LDK + kk);
#pragma unroll
            for (int i = 0; i < 4; ++i)
#pragma unroll
                for (int j = 0; j < 4; ++j)
                    acc[i][j] = __builtin_amdgcn_mfma_f32_16x16x32_bf16(
                        af[i], bfr[j], acc[i][j], 0, 0, 0);
        }
        __syncthreads();
    }

#pragma unroll
    for (int j = 0; j < 4; ++j) {
        const int col = n0 + wn + j * 16 + l16;
        const float bc = bias[col];
#pragma unroll
        for (int i = 0; i < 4; ++i) {
            const int rb = m0 + wm + i * 16 + quad * 4;
#pragma unroll
            for (int r = 0; r < 4; ++r) {
                const int row = rb + r;
                if (row < M) {
                    float v = acc[i][j][r];
                    if constexpr (EPI == 0) {
                        v += srow[row % 17] * bc;
                        v = fmaxf(v, 0.0f);
                        ((bf16*)Cout)[(size_t)row * ldc + col] = __float2bfloat16(v);
                    } else if constexpr (EPI == 1) {
                        v += bc;
                        v = fmaxf(v, 0.0f);
                        ((bf16*)Cout)[(size_t)row * ldc + col] = __float2bfloat16(v);
                    } else {
                        v += bc;
                        ((float*)Cout)[(size_t)row * ldc + col] = v;
                    }
                }
            }
        }
    }
}

// ---------------- K2.5: per-channel sum / sumsq over all rows ------------------
__global__ __launch_bounds__(256)
void k_stats(const bf16* __restrict__ h, float* __restrict__ stats)
{
    const int t  = threadIdx.x;
    const int c0 = (t & 127) * 2;
    const int rs = t >> 7;
    float s0 = 0, s1 = 0, q0 = 0, q1 = 0;
    for (int r = blockIdx.x * 2 + rs; r < RROWS; r += 1024) {   // grid = 512 blocks
        const ushort2 u = *(const ushort2*)(h + (size_t)r * 256 + c0);
        const float v0 = bf2f(u.x), v1 = bf2f(u.y);
        s0 += v0; q0 += v0 * v0;
        s1 += v1; q1 += v1 * v1;
    }
    atomicAdd(&stats[c0], s0);
    atomicAdd(&stats[c0 + 1], s1);
    atomicAdd(&stats[256 + c0], q0);
    atomicAdd(&stats[256 + c0 + 1], q1);
}

// ---------------- K3: BN (global stats) + LN (per row) -> bf16 -----------------
__global__ __launch_bounds__(256)
void k_norm(const bf16* __restrict__ h, bf16* __restrict__ hn,
            const float* __restrict__ stats,
            const float* __restrict__ bng, const float* __restrict__ bnb,
            const float* __restrict__ lng, const float* __restrict__ lnb)
{
    __shared__ float sm[256], sv[256], sg[256], sb[256], sl[256], so[256];
    const int t = threadIdx.x;
    {
        const float mu  = stats[t] * (1.0f / RROWS);
        const float var = stats[256 + t] * (1.0f / RROWS) - mu * mu;
        sm[t] = mu; sv[t] = rsqrtf(var + EPSV);
        sg[t] = bng[t]; sb[t] = bnb[t]; sl[t] = lng[t]; so[t] = lnb[t];
    }
    __syncthreads();
    const int wave = t >> 6, lane = t & 63;
    const int c = lane * 4;
    float mn[4], rs[4], gg[4], bb[4], lg[4], lb[4];
#pragma unroll
    for (int k = 0; k < 4; ++k) {
        mn[k] = sm[c + k]; rs[k] = sv[c + k]; gg[k] = sg[c + k];
        bb[k] = sb[c + k]; lg[k] = sl[c + k]; lb[k] = so[c + k];
    }
    for (int row = blockIdx.x * 4 + wave; row < RROWS; row += 8192) { // grid = 2048
        const ushort4 u = *(const ushort4*)(h + (size_t)row * 256 + c);
        float v[4] = { bf2f(u.x), bf2f(u.y), bf2f(u.z), bf2f(u.w) };
        float s = 0.0f, q = 0.0f;
#pragma unroll
        for (int k = 0; k < 4; ++k) {
            v[k] = (v[k] - mn[k]) * rs[k] * gg[k] + bb[k];
            s += v[k]; q += v[k] * v[k];
        }
#pragma unroll
        for (int off = 32; off > 0; off >>= 1) {
            s += __shfl_xor(s, off);
            q += __shfl_xor(q, off);
        }
        const float lmu = s * (1.0f / 256.0f);
        const float lrs = rsqrtf(q * (1.0f / 256.0f) - lmu * lmu + EPSV);
        ushort4 o;
        o.x = f2bf((v[0] - lmu) * lrs * lg[0] + lb[0]);
        o.y = f2bf((v[1] - lmu) * lrs * lg[1] + lb[1]);
        o.z = f2bf((v[2] - lmu) * lrs * lg[2] + lb[2]);
        o.w = f2bf((v[3] - lmu) * lrs * lg[3] + lb[3]);
        *(ushort4*)(hn + (size_t)row * 256 + c) = o;
    }
}

extern "C" void kernel_launch(void* const* d_in, const int* in_sizes, int n_in,
                              void* d_out, int out_size, void* d_ws, size_t ws_size,
                              hipStream_t stream)
{
    const float* x   = (const float*)d_in[0];
    const float* adj = (const float*)d_in[1];
    const float* w1  = (const float*)d_in[2];
    const float* b1  = (const float*)d_in[3];
    const float* w2  = (const float*)d_in[4];
    const float* b2  = (const float*)d_in[5];
    const float* bng = (const float*)d_in[6];
    const float* bnb = (const float*)d_in[7];
    const float* lng = (const float*)d_in[8];
    const float* lnb = (const float*)d_in[9];
    const float* mw1 = (const float*)d_in[10];
    const float* mb1 = (const float*)d_in[11];
    const float* mw2 = (const float*)d_in[12];
    const float* mb2 = (const float*)d_in[13];

    char* ws = (char*)d_ws;
    const size_t SZ1 = (size_t)RROWS * 256 * 2;          // 135,364,608 B
    bf16* xa  = (bf16*)(ws);                             // xa, later reused as hn
    bf16* h   = (bf16*)(ws + SZ1);                       // h; dead after k_norm
    bf16* mid = (bf16*)(ws + SZ1);                       // mid overlays h (R x 512)
    char* wp  = ws + SZ1 + (size_t)RROWS * 512 * 2;      // 406,093,824 B
    bf16*  wsum  = (bf16*)(wp);
    bf16*  w1m   = (bf16*)(wp + 131072);
    bf16*  w2m   = (bf16*)(wp + 131072 + 262144);
    float* bsum  = (float*)(wp + 131072 + 262144 + 262144);
    float* srow  = (float*)((char*)bsum + 1024);
    float* stats = (float*)((char*)srow + 128);

    const int mt = (RROWS + 127) / 128;                  // 2066

    k_prep<<<512, 256, 0, stream>>>(w1, b1, w2, b2, mw1, mw2, adj,
                                    wsum, w1m, w2m, bsum, srow, stats);
    k_agg<<<NGRP, 256, 0, stream>>>(x, adj, xa);
    gemm_bt<256, 0><<<dim3(2, mt), 256, 0, stream>>>(xa, wsum, h, RROWS, bsum, srow);
    k_stats<<<512, 256, 0, stream>>>(h, stats);
    k_norm<<<2048, 256, 0, stream>>>(h, xa, stats, bng, bnb, lng, lnb);
    gemm_bt<256, 1><<<dim3(4, mt), 256, 0, stream>>>(xa, w1m, mid, RROWS, mb1, nullptr);
    gemm_bt<512, 2><<<dim3(2, mt), 256, 0, stream>>>(mid, w2m, d_out, RROWS, mb2, nullptr);
}